// Round 6
// baseline (831.700 us; speedup 1.0000x reference)
//
#include <hip/hip_runtime.h>
#include <hip/hip_bf16.h>
#include <math.h>

// B=8 N=196 D=512 M=20 K=77 H=8 hd=64, keep=51.  All inputs/outputs fp32.
// out1 = Qs/nrm (B,N,D,M) 16,056,320 fl; out2 = attn_weights (B,K,N) 120,736 fl
// Workspace (fp32 words):
//  WT @0:786432  OWT @786432:262144  q @1048576:39424  kmat @1088000:802816
//  vmat @1890816:802816  attf @2693632:965888  attw @3659520:120736
//  ctx @3780256:315392  AO @4095648:315392  Qp @4411040:31360
//  W1hi(fp16) @4442400: 131072 fl  W1lo(fp16) @4573472: 131072 fl  -> 4704544 fl = 18.8 MB

typedef unsigned int uint;
typedef _Float16 f16x8 __attribute__((ext_vector_type(8)));
typedef float f32x4 __attribute__((ext_vector_type(4)));

#define DI __device__ __forceinline__

DI float wsumf(float v){ for(int o=32;o>0;o>>=1) v += __shfl_xor(v,o,64); return v; }
DI int   wsumi(int v){ for(int o=32;o>0;o>>=1) v += __shfl_xor(v,o,64); return v; }
DI float wmaxf(float v){ for(int o=32;o>0;o>>=1) v = fmaxf(v,__shfl_xor(v,o,64)); return v; }

// ---------------- K0: tiled transposes + W1 split/swizzle ----------------
__global__ __launch_bounds__(256) void k0_transpose(const float* ipw, const float* ow, const float* mw1,
                             float* WT, float* OWT, _Float16* w1hi, _Float16* w1lo){
  int bid = blockIdx.x;
  if(bid < 768){
    __shared__ float t[32][33];
    int tdin = bid & 15, tdout = bid >> 4;
    int tx = threadIdx.x & 31, ty = threadIdx.x >> 5;
    int dout0 = tdout*32, din0 = tdin*32;
    for(int r=ty; r<32; r+=8) t[r][tx] = ipw[(size_t)(dout0+r)*512 + din0+tx];
    __syncthreads();
    for(int r=ty; r<32; r+=8) WT[(size_t)(din0+r)*1536 + dout0+tx] = t[tx][r];
  } else if(bid < 1024){
    __shared__ float t[32][33];
    int b2 = bid - 768;
    int tdin = b2 & 15, tdout = b2 >> 4;
    int tx = threadIdx.x & 31, ty = threadIdx.x >> 5;
    int dout0 = tdout*32, din0 = tdin*32;
    for(int r=ty; r<32; r+=8) t[r][tx] = ow[(size_t)(dout0+r)*512 + din0+tx];
    __syncthreads();
    for(int r=ty; r<32; r+=8) OWT[(size_t)(din0+r)*512 + dout0+tx] = t[tx][r];
  } else {
    int i3 = (bid-1024)*256 + threadIdx.x;
    int t = i3&7, ln = (i3>>3)&63, J = (i3>>9)&31, T = i3>>14;
    int j = J*16 + (ln&15);
    int d = T*32 + ((ln>>4)<<3) + t;
    float w = mw1[j*512 + d] * 64.0f;
    _Float16 hi = (_Float16)w;
    _Float16 lo = (_Float16)(w - (float)hi);
    w1hi[i3] = hi; w1lo[i3] = lo;
  }
}

// ---------------- K1: q = LN(text) @ Wq^T + bq  (154 blocks: k x half) ----------------
__global__ __launch_bounds__(256) void k1_q(const float* text, const float* ipb,
                                            const float* g1, const float* b1p,
                                            const float* WT, float* qws){
  int k = blockIdx.x >> 1, half = blockIdx.x & 1;
  int tid = threadIdx.x;
  __shared__ float xln[512];
  __shared__ float rA[4], rB[4];
  float x0 = text[k*512+tid], x1 = text[k*512+256+tid];
  float s1 = wsumf(x0+x1), s2 = wsumf(x0*x0+x1*x1);
  int w = tid>>6, ln = tid&63;
  if(!ln){ rA[w]=s1; rB[w]=s2; }
  __syncthreads();
  float mu = (rA[0]+rA[1]+rA[2]+rA[3])*(1.f/512.f);
  float var = (rB[0]+rB[1]+rB[2]+rB[3])*(1.f/512.f) - mu*mu;
  float rs = 1.f/sqrtf(fmaxf(var,0.f) + 1e-5f);
  xln[tid]     = (x0-mu)*rs*g1[tid]     + b1p[tid];
  xln[tid+256] = (x1-mu)*rs*g1[tid+256] + b1p[tid+256];
  __syncthreads();
  int d = half*256 + tid;
  float a = ipb[d];
  for(int din=0; din<512; ++din) a += xln[din] * WT[din*1536 + d];
  qws[k*512+d] = a;
}

// ---------------- K2: k = LN(F)@Wk^T+bk, v = F@Wv^T+bv  (512 thr) ----------------
__global__ __launch_bounds__(512) void k2_kv(const float* F, const float* ipb,
                                             const float* g1, const float* b1p,
                                             const float* WT, float* kmat, float* vmat){
  int r0 = blockIdx.x*8; int tid = threadIdx.x;
  __shared__ float xs[8][512];
  __shared__ float xl[8][512];
  __shared__ float red[8][64];
  __shared__ float mu8[8], rs8[8];
  for(int e=tid; e<4096; e+=512){ int r=e>>9, d=e&511; xs[r][d] = F[(size_t)(r0+r)*512 + d]; }
  __syncthreads();
  {
    int r = tid>>6, t = tid&63; float s=0.f, q=0.f;
    for(int i=0;i<8;++i){ float v = xs[r][t+64*i]; s+=v; q+=v*v; }
    red[r][t] = s; __syncthreads();
    if(tid<8){ float ss=0; for(int i=0;i<64;++i) ss+=red[tid][i]; mu8[tid]=ss*(1.f/512.f); }
    __syncthreads();
    red[r][t] = q; __syncthreads();
    if(tid<8){ float qq=0; for(int i=0;i<64;++i) qq+=red[tid][i];
      float m=mu8[tid]; rs8[tid]=1.f/sqrtf(fmaxf(qq*(1.f/512.f)-m*m,0.f)+1e-5f); }
    __syncthreads();
  }
  for(int e=tid; e<4096; e+=512){ int r=e>>9, d=e&511;
    xl[r][d] = (xs[r][d]-mu8[r])*rs8[r]*g1[d] + b1p[d]; }
  __syncthreads();
  int d=tid;
  float ak[8], av[8];
  float bk=ipb[512+d], bv=ipb[1024+d];
  #pragma unroll
  for(int r=0;r<8;++r){ ak[r]=bk; av[r]=bv; }
  for(int din=0; din<512; din+=4){
    float wk[4], wv[4];
    #pragma unroll
    for(int u=0;u<4;++u){ wk[u]=WT[(din+u)*1536+512+d]; wv[u]=WT[(din+u)*1536+1024+d]; }
    #pragma unroll
    for(int r=0;r<8;++r){
      float4 a4 = *(const float4*)&xl[r][din];
      float4 x4 = *(const float4*)&xs[r][din];
      ak[r] += a4.x*wk[0]+a4.y*wk[1]+a4.z*wk[2]+a4.w*wk[3];
      av[r] += x4.x*wv[0]+x4.y*wv[1]+x4.z*wv[2]+x4.w*wv[3];
    }
  }
  #pragma unroll
  for(int r=0;r<8;++r){
    size_t base = (size_t)(r0+r)*512;
    kmat[base+d]=ak[r]; vmat[base+d]=av[r];
  }
}

// ---------------- K3: scores + softmax (640 blocks: kc x b x h) ----------------
__global__ __launch_bounds__(256) void k3_attn(const float* qws, const float* kmat, float* attf){
  int bid = blockIdx.x;
  int kc = bid>>6, b = (bid>>3)&7, h = bid&7;
  int tid = threadIdx.x; int n = tid; int w = tid>>6, ln = tid&63;
  __shared__ float qb[8][64];
  __shared__ float rM[8][4], rS[8][4];
  float4 kr[16];
  if(n < 196){
    const float4* kp = (const float4*)(kmat + ((size_t)(b*196+n))*512 + h*64);
    #pragma unroll
    for(int j=0;j<16;++j) kr[j] = kp[j];
  }
  int kbase = kc*8;
  for(int e=tid; e<512; e+=256){ int kk=e>>6, j=e&63; int k=kbase+kk;
    qb[kk][j] = (k<77)? qws[k*512 + h*64 + j] : 0.f; }
  __syncthreads();
  float sc[8];
  #pragma unroll
  for(int kk=0;kk<8;++kk){
    float s = 0.f;
    if(n<196){
      const float4* q4 = (const float4*)qb[kk];
      #pragma unroll
      for(int j=0;j<16;++j){ float4 q = q4[j];
        s += q.x*kr[j].x + q.y*kr[j].y + q.z*kr[j].z + q.w*kr[j].w; }
      sc[kk] = s*0.125f;
    } else sc[kk] = -INFINITY;
  }
  #pragma unroll
  for(int kk=0;kk<8;++kk){ float m = wmaxf(sc[kk]); if(!ln) rM[kk][w]=m; }
  __syncthreads();
  float ex[8];
  #pragma unroll
  for(int kk=0;kk<8;++kk){
    float m = fmaxf(fmaxf(rM[kk][0],rM[kk][1]),fmaxf(rM[kk][2],rM[kk][3]));
    float e = expf(sc[kk]-m);
    ex[kk]=e;
    float s = wsumf(e); if(!ln) rS[kk][w]=s;
  }
  __syncthreads();
  #pragma unroll
  for(int kk=0;kk<8;++kk){
    int k = kbase+kk;
    if(k<77 && n<196){
      float tot = rS[kk][0]+rS[kk][1]+rS[kk][2]+rS[kk][3];
      attf[(((size_t)(b*8+h))*77 + k)*196 + n] = ex[kk]/tot;
    }
  }
}

// ---------------- K4: ctx = attn @ v (640 blocks: kc x b x h) ----------------
__global__ __launch_bounds__(256) void k4_ctx(const float* attf, const float* vmat, float* ctx){
  int bid = blockIdx.x;
  int kc = bid>>6, b = (bid>>3)&7, h = bid&7;
  int tid = threadIdx.x; int ng = tid>>6, j = tid&63;
  __shared__ float vT[196][64];
  __shared__ float aT[8][196];
  __shared__ float red[8][4][64];
  for(int e=tid; e<196*16; e+=256){ int n=e>>4, jc=e&15;
    const float4* vp = (const float4*)(vmat + ((size_t)(b*196+n))*512 + h*64);
    *(float4*)&vT[n][jc*4] = vp[jc];
  }
  int kbase=kc*8;
  for(int e=tid; e<8*196; e+=256){ int kk=e/196, n=e-kk*196; int k=kbase+kk;
    aT[kk][n] = (k<77)? attf[(((size_t)(b*8+h))*77+k)*196+n] : 0.f; }
  __syncthreads();
  float vr[49];
  #pragma unroll
  for(int t=0;t<49;++t) vr[t] = vT[ng*49+t][j];
  #pragma unroll
  for(int kk=0;kk<8;++kk){
    float p=0.f;
    #pragma unroll
    for(int t=0;t<49;++t) p += aT[kk][ng*49+t]*vr[t];
    red[kk][ng][j]=p;
  }
  __syncthreads();
  for(int e=tid; e<512; e+=256){ int kk=e>>6, j2=e&63; int k=kbase+kk;
    if(k<77){
      float s = red[kk][0][j2]+red[kk][1][j2]+red[kk][2][j2]+red[kk][3][j2];
      ctx[((size_t)(b*77+k))*512 + h*64 + j2] = s;
    } }
}

// ---------------- K5: attn_weights = mean over H ----------------
__global__ void k5_attw(const float* attf, float* attw, float* out2){
  int idx = blockIdx.x*256+threadIdx.x;
  if(idx >= 8*77*196) return;
  int b = idx / (77*196); int rem = idx - b*(77*196);
  float s=0.f;
  #pragma unroll
  for(int h=0;h<8;++h) s += attf[((size_t)(b*8+h))*77*196 + rem];
  s *= 0.125f;
  attw[idx]=s; out2[idx]=s;
}

// ---------------- K6: AO = LN2(ctx @ out_w^T + out_b)  (512 thr) ----------------
__global__ __launch_bounds__(512) void k6_ao(const float* ctx, const float* OWT,
                                             const float* ob, const float* g2, const float* b2p,
                                             float* AO){
  int R0 = blockIdx.x*8; int tid = threadIdx.x;
  __shared__ float xs[8][512];
  __shared__ float ao[8][512];
  __shared__ float red[8][64];
  __shared__ float mu8[8], rs8[8];
  for(int e=tid;e<4096;e+=512){ int r=e>>9,d=e&511; xs[r][d]=ctx[(size_t)(R0+r)*512+d]; }
  __syncthreads();
  int d=tid;
  float a[8]; float obv=ob[d];
  #pragma unroll
  for(int r=0;r<8;++r) a[r]=obv;
  for(int din=0;din<512;din+=4){
    float wv[4];
    #pragma unroll
    for(int u=0;u<4;++u) wv[u]=OWT[(din+u)*512+d];
    #pragma unroll
    for(int r=0;r<8;++r){
      float4 x4 = *(const float4*)&xs[r][din];
      a[r] += x4.x*wv[0]+x4.y*wv[1]+x4.z*wv[2]+x4.w*wv[3];
    }
  }
  #pragma unroll
  for(int r=0;r<8;++r) ao[r][d]=a[r];
  __syncthreads();
  {
    int r=tid>>6,t=tid&63; float s=0.f,q=0.f;
    for(int i=0;i<8;++i){ float v=ao[r][t+64*i]; s+=v; q+=v*v; }
    red[r][t]=s; __syncthreads();
    if(tid<8){ float ss=0; for(int i=0;i<64;++i) ss+=red[tid][i]; mu8[tid]=ss*(1.f/512.f); }
    __syncthreads(); red[r][t]=q; __syncthreads();
    if(tid<8){ float qq=0; for(int i=0;i<64;++i) qq+=red[tid][i];
      float m=mu8[tid]; rs8[tid]=1.f/sqrtf(fmaxf(qq*(1.f/512.f)-m*m,0.f)+1e-5f); }
    __syncthreads();
  }
  for(int e=tid;e<4096;e+=512){ int r=e>>9,dd=e&511;
    AO[(size_t)(R0+r)*512+dd] = (ao[r][dd]-mu8[r])*rs8[r]*g2[dd] + b2p[dd]; }
}

// ---------------- K7: per-(b,n) fused MLP via split-fp16 MFMA -> Qp ----------------
// 1024 thr / 16 waves; wave w: 5 m-tiles x 2 j-tiles -> acc 40 VGPR.
// amdgpu_waves_per_eu(4,4): pin 4 waves/EU -> 128-VGPR budget. R5 showed the
// compiler otherwise picks 64 VGPR (8/EU heuristic) and spills ~22 dw/thread
// (WRITE_SIZE 144 MB). Live set ~90 fits 128 with zero spill.
__global__ __launch_bounds__(1024)
__attribute__((amdgpu_waves_per_eu(4,4)))
void k7_mlp(const float* F, const float* AO, const float* attw,
                                              const _Float16* w1hi, const _Float16* w1lo,
                                              const float* b1p, const float* lng, const float* lnb,
                                              const float* w2, const float* b2p,
                                              float* Qpws){
  int bn = blockIdx.x; int b = bn/196, n = bn - b*196;
  int tid = threadIdx.x; int w = tid>>6, ln = tid&63;
  int col = ln&15, quad = ln>>4;
  __shared__ __align__(16) _Float16 Ah[2][2560];
  __shared__ __align__(16) _Float16 Al[2][2560];
  __shared__ float Fv[512], Sv[512], b1s[512], gs[512], bs[512];
  __shared__ float SvP[512];
  __shared__ float wvS[80];
  __shared__ float redS[16][80], redQ[16][80];
  __shared__ float mu80[80], rs80[80];
  __shared__ float gfin[512];
  __shared__ float qred[320];
  __shared__ float wsumS;

  const float* AObase = AO + (size_t)b*77*512;
  if(tid<512){
    Fv[tid]  = F[(size_t)bn*512 + tid];
    b1s[tid] = b1p[tid]; gs[tid] = lng[tid]; bs[tid] = lnb[tid];
  } else if(tid<592){
    int k=tid-512; wvS[k] = (k<77)? attw[((size_t)(b*77+k))*196+n] : 0.f;
  }
  __syncthreads();
  {
    int d = tid & 511, half = tid >> 9;
    float sv = 0.f;
    int klo = half? 39:0, khi = half? 77:39;
    for(int k=klo;k<khi;++k) sv += wvS[k]*AObase[k*512 + d];
    if(half) SvP[d] = sv;
    __syncthreads();
    if(!half) Sv[d] = (sv + SvP[d])*(1.f/77.f);
  }
  if(tid==0){ float s=0.f; for(int k=0;k<77;++k) s+=wvS[k]; wsumS=s; }
  __syncthreads();

  int sk[3], sdd[3]; bool sval[3];
  #pragma unroll
  for(int it=0; it<3; ++it){ int i = tid + it*1024; sval[it] = (i<2560); sk[it] = i>>5; sdd[it] = i&31; }

  // stage step 0 into buf 0
  #pragma unroll
  for(int it=0; it<3; ++it){
    if(sval[it]){
      int k = sk[it], dd = sdd[it];
      float a = (k<77)? AObase[k*512 + dd] : 0.f;
      float cl = (k<77)? Fv[dd]*(wvS[k]*a - Sv[dd])*1024.f : 0.f;
      _Float16 hi = (_Float16)cl;
      _Float16 lo = (_Float16)(cl - (float)hi);
      int idx = ((k>>4)<<9) + ((((k&15)|((dd>>3)<<4)))<<3) + (dd&7);
      Ah[0][idx]=hi; Al[0][idx]=lo;
    }
  }
  __syncthreads();

  f32x4 acc[5][2];
  #pragma unroll
  for(int mt=0;mt<5;++mt)
    #pragma unroll
    for(int jj=0;jj<2;++jj) acc[mt][jj] = (f32x4){0.f,0.f,0.f,0.f};

  for(int t=0; t<16; ++t){
    int buf = t&1, nbuf = buf^1;
    f16x8 Bh[2], Bl[2];
    #pragma unroll
    for(int jj=0;jj<2;++jj){
      int base = (((t*32 + (w*2+jj))*64) + ln)*8;
      Bh[jj] = *(const f16x8*)(w1hi + base);
      Bl[jj] = *(const f16x8*)(w1lo + base);
    }
    float aopre[3];
    int d0n = (t+1)*32;
    if(t<15){
      #pragma unroll
      for(int it=0; it<3; ++it){
        if(sval[it]){ int k = sk[it];
          aopre[it] = (k<77)? AObase[k*512 + d0n + sdd[it]] : 0.f; }
      }
    }
    #pragma unroll
    for(int mt=0;mt<5;++mt){
      f16x8 Afh = *(const f16x8*)&Ah[buf][mt*512 + ln*8];
      f16x8 Afl = *(const f16x8*)&Al[buf][mt*512 + ln*8];
      #pragma unroll
      for(int jj=0;jj<2;++jj)
        acc[mt][jj] = __builtin_amdgcn_mfma_f32_16x16x32_f16(Afl, Bh[jj], acc[mt][jj], 0,0,0);
      #pragma unroll
      for(int jj=0;jj<2;++jj)
        acc[mt][jj] = __builtin_amdgcn_mfma_f32_16x16x32_f16(Afh, Bl[jj], acc[mt][jj], 0,0,0);
      #pragma unroll
      for(int jj=0;jj<2;++jj)
        acc[mt][jj] = __builtin_amdgcn_mfma_f32_16x16x32_f16(Afh, Bh[jj], acc[mt][jj], 0,0,0);
    }
    if(t<15){
      #pragma unroll
      for(int it=0; it<3; ++it){
        if(sval[it]){
          int k = sk[it], dd = sdd[it]; int d = d0n + dd;
          float cl = (k<77)? Fv[d]*(wvS[k]*aopre[it] - Sv[d])*1024.f : 0.f;
          _Float16 hi = (_Float16)cl;
          _Float16 lo = (_Float16)(cl - (float)hi);
          int idx = ((k>>4)<<9) + ((((k&15)|((dd>>3)<<4)))<<3) + (dd&7);
          Ah[nbuf][idx]=hi; Al[nbuf][idx]=lo;
        }
      }
    }
    __syncthreads();
  }

  const float UNS = 1.f/65536.f;
  #pragma unroll
  for(int mt=0;mt<5;++mt){
    float s[4]={0.f,0.f,0.f,0.f}, q[4]={0.f,0.f,0.f,0.f};
    #pragma unroll
    for(int jj=0;jj<2;++jj){
      int j = w*32 + jj*16 + col; float bj = b1s[j];
      #pragma unroll
      for(int r=0;r<4;++r){
        float h = acc[mt][jj][r]*UNS + bj;
        s[r]+=h; q[r]+=h*h;
      }
    }
    #pragma unroll
    for(int r=0;r<4;++r){
      #pragma unroll
      for(int o=1;o<16;o<<=1){ s[r]+=__shfl_xor(s[r],o,64); q[r]+=__shfl_xor(q[r],o,64); }
    }
    if(col==0){
      #pragma unroll
      for(int r=0;r<4;++r){ int row = mt*16+quad*4+r; redS[w][row]=s[r]; redQ[w][row]=q[r]; }
    }
  }
  __syncthreads();
  if(tid<80){
    float s=0.f,q=0.f;
    #pragma unroll
    for(int ww=0;ww<16;++ww){ s+=redS[ww][tid]; q+=redQ[ww][tid]; }
    float mu = s*(1.f/512.f);
    float var = q*(1.f/512.f)-mu*mu;
    mu80[tid]=mu; rs80[tid]=1.f/sqrtf(fmaxf(var,0.f)+1e-5f);
  }
  __syncthreads();
  float gp[2]={0.f,0.f};
  #pragma unroll
  for(int mt=0;mt<5;++mt){
    #pragma unroll
    for(int r=0;r<4;++r){
      int row = mt*16+quad*4+r;
      float mu=mu80[row], rs=rs80[row], wk=wvS[row];
      #pragma unroll
      for(int jj=0;jj<2;++jj){
        int j = w*32 + jj*16 + col;
        float h = acc[mt][jj][r]*UNS + b1s[j];
        float x = (h-mu)*rs;
        float y = x*gs[j]+bs[j];
        float gl = 0.5f*y*(1.f+erff(y*0.70710678118654752f));
        gp[jj] += wk*gl;
      }
    }
  }
  #pragma unroll
  for(int jj=0;jj<2;++jj){ gp[jj]+=__shfl_xor(gp[jj],16,64); gp[jj]+=__shfl_xor(gp[jj],32,64); }
  if(ln<16){
    #pragma unroll
    for(int jj=0;jj<2;++jj) gfin[w*32 + jj*16 + ln] = gp[jj];
  }
  __syncthreads();
  if(tid<320){ int m=tid>>4, seg=tid&15; float p=0.f;
    for(int u=0;u<32;++u){ int j=seg*32+u; p += gfin[j]*w2[m*512+j]; }
    qred[m*16+seg]=p; }
  __syncthreads();
  if(tid<20){ float s=0.f;
    for(int seg=0;seg<16;++seg) s+=qred[tid*16+seg];
    s += b2p[tid]*wsumS;
    Qpws[(size_t)bn*20+tid]=s; }
}

// ---------------- K8: per-(b,n) top-51 mask + normalize -> out1 ----------------
__global__ __launch_bounds__(256) void k8_topk(const float* F, const float* T,
                                               const float* Qpws, float* out1){
  int bn = blockIdx.x; int tid = threadIdx.x;
  int w = tid>>6, ln = tid&63;
  __shared__ float Fv[512];
  __shared__ float QpS[20];
  __shared__ float ninv[20];
  __shared__ unsigned char selb[20][64];
  for(int e=tid;e<512;e+=256) Fv[e]=F[(size_t)bn*512+e];
  if(tid<20) QpS[tid]=Qpws[(size_t)bn*20+tid];
  __syncthreads();
  for(int rr=0; rr<5; ++rr){
    int m = rr*4 + w;
    float qv[8]; uint key[8];
    const float4* tp = (const float4*)(T + (size_t)m*512 + ln*8);
    float4 t0 = tp[0], t1 = tp[1];
    float tf[8] = {t0.x,t0.y,t0.z,t0.w,t1.x,t1.y,t1.z,t1.w};
    float qp = QpS[m];
    #pragma unroll
    for(int i=0;i<8;++i){ float p = Fv[ln*8+i]*tf[i]; qv[i]=p*qp;
      key[i]=__float_as_uint(qv[i])&0x7fffffffu; }
    uint th=0u;
    for(int bit=30; bit>=0; --bit){
      uint cand = th | (1u<<bit);
      int c=0;
      #pragma unroll
      for(int i=0;i<8;++i) c += (key[i]>=cand);
      c = wsumi(c);
      if(c>=51) th=cand;
    }
    int cg=0;
    #pragma unroll
    for(int i=0;i<8;++i) cg += (key[i]>th);
    cg = wsumi(cg);
    int rneed = 51-cg;
    int eqc=0;
    #pragma unroll
    for(int i=0;i<8;++i) eqc += (key[i]==th);
    int pre=eqc;
    for(int o=1;o<64;o<<=1){ int v=__shfl_up(pre,o,64); if(ln>=o) pre+=v; }
    pre -= eqc;
    unsigned char mbits=0; float ss=0.f; int rk=pre;
    #pragma unroll
    for(int i=0;i<8;++i){
      bool s;
      if(key[i]>th) s=true;
      else if(key[i]==th){ s = (rk<rneed); rk++; }
      else s=false;
      if(s){ mbits |= (unsigned char)(1u<<i); ss += qv[i]*qv[i]; }
    }
    ss = wsumf(ss);
    if(ln==0) ninv[m] = 1.f/fmaxf(sqrtf(ss),1e-6f);
    selb[m][ln]=mbits;
  }
  __syncthreads();
  size_t base=(size_t)bn*10240;
  for(int e=tid;e<10240;e+=256){
    int d=e/20, mm=e-d*20;
    float val=0.f;
    if((selb[mm][d>>3]>>(d&7))&1){
      val = Fv[d]*T[(size_t)mm*512+d]*QpS[mm]*ninv[mm];
    }
    out1[base+e]=val;
  }
}

extern "C" void kernel_launch(void* const* d_in, const int* in_sizes, int n_in,
                              void* d_out, int out_size, void* d_ws, size_t ws_size,
                              hipStream_t stream){
  const float* F    = (const float*)d_in[0];
  const float* text = (const float*)d_in[1];
  const float* ipw  = (const float*)d_in[2];
  const float* ipb  = (const float*)d_in[3];
  const float* outw = (const float*)d_in[4];
  const float* outb = (const float*)d_in[5];
  const float* g1   = (const float*)d_in[6];
  const float* b1   = (const float*)d_in[7];
  const float* g2   = (const float*)d_in[8];
  const float* b2   = (const float*)d_in[9];
  const float* mw1  = (const float*)d_in[10];
  const float* mb1  = (const float*)d_in[11];
  const float* mlg  = (const float*)d_in[12];
  const float* mlb  = (const float*)d_in[13];
  const float* mw2  = (const float*)d_in[14];
  const float* mb2  = (const float*)d_in[15];
  const float* tmpl = (const float*)d_in[16];
  float* ws = (float*)d_ws;
  float* WT   = ws;
  float* OWT  = ws +  786432;
  float* qws  = ws + 1048576;
  float* kmat = ws + 1088000;
  float* vmat = ws + 1890816;
  float* attf = ws + 2693632;
  float* attw = ws + 3659520;
  float* ctx  = ws + 3780256;
  float* AO   = ws + 4095648;
  float* Qp   = ws + 4411040;
  _Float16* w1hi = (_Float16*)(ws + 4442400);
  _Float16* w1lo = (_Float16*)(ws + 4573472);
  float* out1 = (float*)d_out;
  float* out2 = out1 + 16056320;

  hipLaunchKernelGGL(k0_transpose, dim3(2048), dim3(256), 0, stream, ipw, outw, mw1, WT, OWT, w1hi, w1lo);
  hipLaunchKernelGGL(k1_q,   dim3(154), dim3(256), 0, stream, text, ipb, g1, b1, WT, qws);
  hipLaunchKernelGGL(k2_kv,  dim3(196), dim3(512), 0, stream, F, ipb, g1, b1, WT, kmat, vmat);
  hipLaunchKernelGGL(k3_attn,dim3(640), dim3(256), 0, stream, qws, kmat, attf);
  hipLaunchKernelGGL(k4_ctx, dim3(640), dim3(256), 0, stream, attf, vmat, ctx);
  hipLaunchKernelGGL(k5_attw,dim3(472), dim3(256), 0, stream, attf, attw, out2);
  hipLaunchKernelGGL(k6_ao,  dim3(77),  dim3(512), 0, stream, ctx, OWT, outb, g2, b2, AO);
  hipLaunchKernelGGL(k7_mlp, dim3(1568),dim3(1024), 0, stream, F, AO, attw, w1hi, w1lo, mb1, mlg, mlb, mw2, mb2, Qp);
  hipLaunchKernelGGL(k8_topk,dim3(1568),dim3(256), 0, stream, F, tmpl, Qp, out1);
}

// Round 7
// 733.317 us; speedup vs baseline: 1.1342x; 1.1342x over previous
//
#include <hip/hip_runtime.h>
#include <hip/hip_bf16.h>
#include <math.h>

// B=8 N=196 D=512 M=20 K=77 H=8 hd=64, keep=51.  All inputs/outputs fp32.
// out1 = Qs/nrm (B,N,D,M) 16,056,320 fl; out2 = attn_weights (B,K,N) 120,736 fl
// Workspace (fp32 words):
//  WT @0:786432  OWT @786432:262144  q @1048576:39424  kmat @1088000:802816
//  vmat @1890816:802816  attf @2693632:965888  attw @3659520:120736
//  ctx @3780256:315392  AO @4095648:315392  Qp @4411040:31360
//  W1hi(fp16) @4442400: 131072 fl  W1lo(fp16) @4573472: 131072 fl  -> 4704544 fl = 18.8 MB

typedef unsigned int uint;
typedef _Float16 f16x8 __attribute__((ext_vector_type(8)));
typedef float f32x4 __attribute__((ext_vector_type(4)));

#define DI __device__ __forceinline__

DI float wsumf(float v){ for(int o=32;o>0;o>>=1) v += __shfl_xor(v,o,64); return v; }
DI int   wsumi(int v){ for(int o=32;o>0;o>>=1) v += __shfl_xor(v,o,64); return v; }
DI float wmaxf(float v){ for(int o=32;o>0;o>>=1) v = fmaxf(v,__shfl_xor(v,o,64)); return v; }

// ---------------- K0: tiled transposes + W1 split/swizzle ----------------
__global__ __launch_bounds__(256) void k0_transpose(const float* ipw, const float* ow, const float* mw1,
                             float* WT, float* OWT, _Float16* w1hi, _Float16* w1lo){
  int bid = blockIdx.x;
  if(bid < 768){
    __shared__ float t[32][33];
    int tdin = bid & 15, tdout = bid >> 4;
    int tx = threadIdx.x & 31, ty = threadIdx.x >> 5;
    int dout0 = tdout*32, din0 = tdin*32;
    for(int r=ty; r<32; r+=8) t[r][tx] = ipw[(size_t)(dout0+r)*512 + din0+tx];
    __syncthreads();
    for(int r=ty; r<32; r+=8) WT[(size_t)(din0+r)*1536 + dout0+tx] = t[tx][r];
  } else if(bid < 1024){
    __shared__ float t[32][33];
    int b2 = bid - 768;
    int tdin = b2 & 15, tdout = b2 >> 4;
    int tx = threadIdx.x & 31, ty = threadIdx.x >> 5;
    int dout0 = tdout*32, din0 = tdin*32;
    for(int r=ty; r<32; r+=8) t[r][tx] = ow[(size_t)(dout0+r)*512 + din0+tx];
    __syncthreads();
    for(int r=ty; r<32; r+=8) OWT[(size_t)(din0+r)*512 + dout0+tx] = t[tx][r];
  } else {
    int i3 = (bid-1024)*256 + threadIdx.x;
    int t = i3&7, ln = (i3>>3)&63, J = (i3>>9)&31, T = i3>>14;
    int j = J*16 + (ln&15);
    int d = T*32 + ((ln>>4)<<3) + t;
    float w = mw1[j*512 + d] * 64.0f;
    _Float16 hi = (_Float16)w;
    _Float16 lo = (_Float16)(w - (float)hi);
    w1hi[i3] = hi; w1lo[i3] = lo;
  }
}

// ---------------- K1: q = LN(text) @ Wq^T + bq  (154 blocks: k x half) ----------------
__global__ __launch_bounds__(256) void k1_q(const float* text, const float* ipb,
                                            const float* g1, const float* b1p,
                                            const float* WT, float* qws){
  int k = blockIdx.x >> 1, half = blockIdx.x & 1;
  int tid = threadIdx.x;
  __shared__ float xln[512];
  __shared__ float rA[4], rB[4];
  float x0 = text[k*512+tid], x1 = text[k*512+256+tid];
  float s1 = wsumf(x0+x1), s2 = wsumf(x0*x0+x1*x1);
  int w = tid>>6, ln = tid&63;
  if(!ln){ rA[w]=s1; rB[w]=s2; }
  __syncthreads();
  float mu = (rA[0]+rA[1]+rA[2]+rA[3])*(1.f/512.f);
  float var = (rB[0]+rB[1]+rB[2]+rB[3])*(1.f/512.f) - mu*mu;
  float rs = 1.f/sqrtf(fmaxf(var,0.f) + 1e-5f);
  xln[tid]     = (x0-mu)*rs*g1[tid]     + b1p[tid];
  xln[tid+256] = (x1-mu)*rs*g1[tid+256] + b1p[tid+256];
  __syncthreads();
  int d = half*256 + tid;
  float a0=0.f,a1=0.f,a2=0.f,a3=0.f;   // 4 independent chains for ILP
  for(int din=0; din<512; din+=4){
    a0 += xln[din  ] * WT[(din  )*1536 + d];
    a1 += xln[din+1] * WT[(din+1)*1536 + d];
    a2 += xln[din+2] * WT[(din+2)*1536 + d];
    a3 += xln[din+3] * WT[(din+3)*1536 + d];
  }
  qws[k*512+d] = ipb[d] + ((a0+a1)+(a2+a3));
}

// ---------------- K2: k = LN(F)@Wk^T+bk, v = F@Wv^T+bv  (512 thr) ----------------
__global__ __launch_bounds__(512) void k2_kv(const float* F, const float* ipb,
                                             const float* g1, const float* b1p,
                                             const float* WT, float* kmat, float* vmat){
  int r0 = blockIdx.x*8; int tid = threadIdx.x;
  __shared__ float xs[8][512];
  __shared__ float xl[8][512];
  __shared__ float red[8][64];
  __shared__ float mu8[8], rs8[8];
  for(int e=tid; e<4096; e+=512){ int r=e>>9, d=e&511; xs[r][d] = F[(size_t)(r0+r)*512 + d]; }
  __syncthreads();
  {
    int r = tid>>6, t = tid&63; float s=0.f, q=0.f;
    for(int i=0;i<8;++i){ float v = xs[r][t+64*i]; s+=v; q+=v*v; }
    red[r][t] = s; __syncthreads();
    if(tid<8){ float ss=0; for(int i=0;i<64;++i) ss+=red[tid][i]; mu8[tid]=ss*(1.f/512.f); }
    __syncthreads();
    red[r][t] = q; __syncthreads();
    if(tid<8){ float qq=0; for(int i=0;i<64;++i) qq+=red[tid][i];
      float m=mu8[tid]; rs8[tid]=1.f/sqrtf(fmaxf(qq*(1.f/512.f)-m*m,0.f)+1e-5f); }
    __syncthreads();
  }
  for(int e=tid; e<4096; e+=512){ int r=e>>9, d=e&511;
    xl[r][d] = (xs[r][d]-mu8[r])*rs8[r]*g1[d] + b1p[d]; }
  __syncthreads();
  int d=tid;
  float ak[8], av[8];
  float bk=ipb[512+d], bv=ipb[1024+d];
  #pragma unroll
  for(int r=0;r<8;++r){ ak[r]=bk; av[r]=bv; }
  for(int din=0; din<512; din+=4){
    float wk[4], wv[4];
    #pragma unroll
    for(int u=0;u<4;++u){ wk[u]=WT[(din+u)*1536+512+d]; wv[u]=WT[(din+u)*1536+1024+d]; }
    #pragma unroll
    for(int r=0;r<8;++r){
      float4 a4 = *(const float4*)&xl[r][din];
      float4 x4 = *(const float4*)&xs[r][din];
      ak[r] += a4.x*wk[0]+a4.y*wk[1]+a4.z*wk[2]+a4.w*wk[3];
      av[r] += x4.x*wv[0]+x4.y*wv[1]+x4.z*wv[2]+x4.w*wv[3];
    }
  }
  #pragma unroll
  for(int r=0;r<8;++r){
    size_t base = (size_t)(r0+r)*512;
    kmat[base+d]=ak[r]; vmat[base+d]=av[r];
  }
}

// ---------------- K3: scores + softmax (640 blocks: kc x b x h) ----------------
__global__ __launch_bounds__(256) void k3_attn(const float* qws, const float* kmat, float* attf){
  int bid = blockIdx.x;
  int kc = bid>>6, b = (bid>>3)&7, h = bid&7;
  int tid = threadIdx.x; int n = tid; int w = tid>>6, ln = tid&63;
  __shared__ float qb[8][64];
  __shared__ float rM[8][4], rS[8][4];
  float4 kr[16];
  if(n < 196){
    const float4* kp = (const float4*)(kmat + ((size_t)(b*196+n))*512 + h*64);
    #pragma unroll
    for(int j=0;j<16;++j) kr[j] = kp[j];
  }
  int kbase = kc*8;
  for(int e=tid; e<512; e+=256){ int kk=e>>6, j=e&63; int k=kbase+kk;
    qb[kk][j] = (k<77)? qws[k*512 + h*64 + j] : 0.f; }
  __syncthreads();
  float sc[8];
  #pragma unroll
  for(int kk=0;kk<8;++kk){
    float s = 0.f;
    if(n<196){
      const float4* q4 = (const float4*)qb[kk];
      #pragma unroll
      for(int j=0;j<16;++j){ float4 q = q4[j];
        s += q.x*kr[j].x + q.y*kr[j].y + q.z*kr[j].z + q.w*kr[j].w; }
      sc[kk] = s*0.125f;
    } else sc[kk] = -INFINITY;
  }
  #pragma unroll
  for(int kk=0;kk<8;++kk){ float m = wmaxf(sc[kk]); if(!ln) rM[kk][w]=m; }
  __syncthreads();
  float ex[8];
  #pragma unroll
  for(int kk=0;kk<8;++kk){
    float m = fmaxf(fmaxf(rM[kk][0],rM[kk][1]),fmaxf(rM[kk][2],rM[kk][3]));
    float e = expf(sc[kk]-m);
    ex[kk]=e;
    float s = wsumf(e); if(!ln) rS[kk][w]=s;
  }
  __syncthreads();
  #pragma unroll
  for(int kk=0;kk<8;++kk){
    int k = kbase+kk;
    if(k<77 && n<196){
      float tot = rS[kk][0]+rS[kk][1]+rS[kk][2]+rS[kk][3];
      attf[(((size_t)(b*8+h))*77 + k)*196 + n] = ex[kk]/tot;
    }
  }
}

// ---------------- K4: ctx = attn @ v (640 blocks: kc x b x h) ----------------
__global__ __launch_bounds__(256) void k4_ctx(const float* attf, const float* vmat, float* ctx){
  int bid = blockIdx.x;
  int kc = bid>>6, b = (bid>>3)&7, h = bid&7;
  int tid = threadIdx.x; int ng = tid>>6, j = tid&63;
  __shared__ float vT[196][64];
  __shared__ float aT[8][196];
  __shared__ float red[8][4][64];
  for(int e=tid; e<196*16; e+=256){ int n=e>>4, jc=e&15;
    const float4* vp = (const float4*)(vmat + ((size_t)(b*196+n))*512 + h*64);
    *(float4*)&vT[n][jc*4] = vp[jc];
  }
  int kbase=kc*8;
  for(int e=tid; e<8*196; e+=256){ int kk=e/196, n=e-kk*196; int k=kbase+kk;
    aT[kk][n] = (k<77)? attf[(((size_t)(b*8+h))*77+k)*196+n] : 0.f; }
  __syncthreads();
  float vr[49];
  #pragma unroll
  for(int t=0;t<49;++t) vr[t] = vT[ng*49+t][j];
  #pragma unroll
  for(int kk=0;kk<8;++kk){
    float p=0.f;
    #pragma unroll
    for(int t=0;t<49;++t) p += aT[kk][ng*49+t]*vr[t];
    red[kk][ng][j]=p;
  }
  __syncthreads();
  for(int e=tid; e<512; e+=256){ int kk=e>>6, j2=e&63; int k=kbase+kk;
    if(k<77){
      float s = red[kk][0][j2]+red[kk][1][j2]+red[kk][2][j2]+red[kk][3][j2];
      ctx[((size_t)(b*77+k))*512 + h*64 + j2] = s;
    } }
}

// ---------------- K5: attn_weights = mean over H ----------------
__global__ void k5_attw(const float* attf, float* attw, float* out2){
  int idx = blockIdx.x*256+threadIdx.x;
  if(idx >= 8*77*196) return;
  int b = idx / (77*196); int rem = idx - b*(77*196);
  float s=0.f;
  #pragma unroll
  for(int h=0;h<8;++h) s += attf[((size_t)(b*8+h))*77*196 + rem];
  s *= 0.125f;
  attw[idx]=s; out2[idx]=s;
}

// ---------------- K6: AO = LN2(ctx @ out_w^T + out_b)  (512 thr) ----------------
__global__ __launch_bounds__(512) void k6_ao(const float* ctx, const float* OWT,
                                             const float* ob, const float* g2, const float* b2p,
                                             float* AO){
  int R0 = blockIdx.x*8; int tid = threadIdx.x;
  __shared__ float xs[8][512];
  __shared__ float ao[8][512];
  __shared__ float red[8][64];
  __shared__ float mu8[8], rs8[8];
  for(int e=tid;e<4096;e+=512){ int r=e>>9,d=e&511; xs[r][d]=ctx[(size_t)(R0+r)*512+d]; }
  __syncthreads();
  int d=tid;
  float a[8]; float obv=ob[d];
  #pragma unroll
  for(int r=0;r<8;++r) a[r]=obv;
  for(int din=0;din<512;din+=4){
    float wv[4];
    #pragma unroll
    for(int u=0;u<4;++u) wv[u]=OWT[(din+u)*512+d];
    #pragma unroll
    for(int r=0;r<8;++r){
      float4 x4 = *(const float4*)&xs[r][din];
      a[r] += x4.x*wv[0]+x4.y*wv[1]+x4.z*wv[2]+x4.w*wv[3];
    }
  }
  #pragma unroll
  for(int r=0;r<8;++r) ao[r][d]=a[r];
  __syncthreads();
  {
    int r=tid>>6,t=tid&63; float s=0.f,q=0.f;
    for(int i=0;i<8;++i){ float v=ao[r][t+64*i]; s+=v; q+=v*v; }
    red[r][t]=s; __syncthreads();
    if(tid<8){ float ss=0; for(int i=0;i<64;++i) ss+=red[tid][i]; mu8[tid]=ss*(1.f/512.f); }
    __syncthreads(); red[r][t]=q; __syncthreads();
    if(tid<8){ float qq=0; for(int i=0;i<64;++i) qq+=red[tid][i];
      float m=mu8[tid]; rs8[tid]=1.f/sqrtf(fmaxf(qq*(1.f/512.f)-m*m,0.f)+1e-5f); }
    __syncthreads();
  }
  for(int e=tid;e<4096;e+=512){ int r=e>>9,dd=e&511;
    AO[(size_t)(R0+r)*512+dd] = (ao[r][dd]-mu8[r])*rs8[r]*g2[dd] + b2p[dd]; }
}

// ---------------- K7: per-(b,n) fused MLP via split-fp16 MFMA -> Qp ----------------
// 512 thr / 8 waves; wave w: 5 m-tiles x 4 j-tiles -> acc 80 VGPR/thread.
// VGPR-budget model (R3-R6 evidence): backend caps VGPRs at 512/(LDS-limited
// waves/EU). LDS 40KB -> 32 waves/CU -> 8/EU -> cap 128 (R3: spill 14 dw).
// Force LDS > 80KB -> 1 block/CU -> 8 waves -> 2/EU -> cap 256 -> live ~150
// fits with ZERO spill. ldsforce[] kept alive via opaque runtime-false cond.
__global__
__attribute__((amdgpu_flat_work_group_size(512,512)))
__attribute__((amdgpu_waves_per_eu(2,2)))
void k7_mlp(const float* F, const float* AO, const float* attw,
            const _Float16* w1hi, const _Float16* w1lo,
            const float* b1p, const float* lng, const float* lnb,
            const float* w2, const float* b2p,
            float* Qpws){
  int bn = blockIdx.x; int b = bn/196, n = bn - b*196;
  int tid = threadIdx.x; int w = tid>>6, ln = tid&63;
  int col = ln&15, quad = ln>>4;
  __shared__ __align__(16) _Float16 Ah[2][2560];
  __shared__ __align__(16) _Float16 Al[2][2560];
  __shared__ float Fv[512], Sv[512], b1s[512], gs[512], bs[512];
  __shared__ float wvS[80];
  __shared__ float redS[8][80], redQ[8][80];
  __shared__ float mu80[80], rs80[80];
  __shared__ float gfin[512];
  __shared__ float qred[320];
  __shared__ float wsumS;
  __shared__ float ldsforce[10496];   // occupancy clamp: total LDS > 80 KiB

  const float* AObase = AO + (size_t)b*77*512;
  Fv[tid]  = F[(size_t)bn*512 + tid];
  b1s[tid] = b1p[tid]; gs[tid] = lng[tid]; bs[tid] = lnb[tid];
  if(tid<80) wvS[tid] = (tid<77)? attw[((size_t)(b*77+tid))*196+n] : 0.f;
  __syncthreads();
  {
    float sv=0.f;
    for(int k=0;k<77;++k) sv += wvS[k]*AObase[k*512 + tid];
    Sv[tid] = sv*(1.f/77.f);
  }
  if(tid==0){ float s=0.f; for(int k=0;k<77;++k) s+=wvS[k]; wsumS=s; }
  __syncthreads();

  int sk[5], sdd[5];
  #pragma unroll
  for(int it=0; it<5; ++it){ int i = tid + it*512; sk[it] = i>>5; sdd[it] = i&31; }

  // stage step 0 into buf 0
  #pragma unroll
  for(int it=0; it<5; ++it){
    int k = sk[it], dd = sdd[it];
    float a = (k<77)? AObase[k*512 + dd] : 0.f;
    float cl = (k<77)? Fv[dd]*(wvS[k]*a - Sv[dd])*1024.f : 0.f;
    _Float16 hi = (_Float16)cl;
    _Float16 lo = (_Float16)(cl - (float)hi);
    int idx = ((k>>4)<<9) + ((((k&15)|((dd>>3)<<4)))<<3) + (dd&7);
    Ah[0][idx]=hi; Al[0][idx]=lo;
  }
  __syncthreads();

  f32x4 acc[5][4];
  #pragma unroll
  for(int mt=0;mt<5;++mt)
    #pragma unroll
    for(int jj=0;jj<4;++jj) acc[mt][jj] = (f32x4){0.f,0.f,0.f,0.f};

  for(int t=0; t<16; ++t){
    int buf = t&1, nbuf = buf^1;
    f16x8 Bh[4], Bl[4];
    #pragma unroll
    for(int jj=0;jj<4;++jj){
      int base = (((t*32 + (w*4+jj))*64) + ln)*8;
      Bh[jj] = *(const f16x8*)(w1hi + base);
      Bl[jj] = *(const f16x8*)(w1lo + base);
    }
    float aopre[5];
    int d0n = (t+1)*32;
    if(t<15){
      #pragma unroll
      for(int it=0; it<5; ++it){
        int k = sk[it];
        aopre[it] = (k<77)? AObase[k*512 + d0n + sdd[it]] : 0.f;
      }
    }
    #pragma unroll
    for(int mt=0;mt<5;++mt){
      f16x8 Afh = *(const f16x8*)&Ah[buf][mt*512 + ln*8];
      f16x8 Afl = *(const f16x8*)&Al[buf][mt*512 + ln*8];
      #pragma unroll
      for(int jj=0;jj<4;++jj)
        acc[mt][jj] = __builtin_amdgcn_mfma_f32_16x16x32_f16(Afl, Bh[jj], acc[mt][jj], 0,0,0);
      #pragma unroll
      for(int jj=0;jj<4;++jj)
        acc[mt][jj] = __builtin_amdgcn_mfma_f32_16x16x32_f16(Afh, Bl[jj], acc[mt][jj], 0,0,0);
      #pragma unroll
      for(int jj=0;jj<4;++jj)
        acc[mt][jj] = __builtin_amdgcn_mfma_f32_16x16x32_f16(Afh, Bh[jj], acc[mt][jj], 0,0,0);
    }
    if(t<15){
      #pragma unroll
      for(int it=0; it<5; ++it){
        int k = sk[it], dd = sdd[it]; int d = d0n + dd;
        float cl = (k<77)? Fv[d]*(wvS[k]*aopre[it] - Sv[d])*1024.f : 0.f;
        _Float16 hi = (_Float16)cl;
        _Float16 lo = (_Float16)(cl - (float)hi);
        int idx = ((k>>4)<<9) + ((((k&15)|((dd>>3)<<4)))<<3) + (dd&7);
        Ah[nbuf][idx]=hi; Al[nbuf][idx]=lo;
      }
    }
    __syncthreads();
  }

  const float UNS = 1.f/65536.f;
  #pragma unroll
  for(int mt=0;mt<5;++mt){
    float s[4]={0.f,0.f,0.f,0.f}, q[4]={0.f,0.f,0.f,0.f};
    #pragma unroll
    for(int jj=0;jj<4;++jj){
      int j = w*64 + jj*16 + col; float bj = b1s[j];
      #pragma unroll
      for(int r=0;r<4;++r){
        float h = acc[mt][jj][r]*UNS + bj;
        s[r]+=h; q[r]+=h*h;
      }
    }
    #pragma unroll
    for(int r=0;r<4;++r){
      #pragma unroll
      for(int o=1;o<16;o<<=1){ s[r]+=__shfl_xor(s[r],o,64); q[r]+=__shfl_xor(q[r],o,64); }
    }
    if(col==0){
      #pragma unroll
      for(int r=0;r<4;++r){ int row = mt*16+quad*4+r; redS[w][row]=s[r]; redQ[w][row]=q[r]; }
    }
  }
  __syncthreads();
  if(tid<80){
    float s=0.f,q=0.f;
    #pragma unroll
    for(int ww=0;ww<8;++ww){ s+=redS[ww][tid]; q+=redQ[ww][tid]; }
    float mu = s*(1.f/512.f);
    float var = q*(1.f/512.f)-mu*mu;
    mu80[tid]=mu; rs80[tid]=1.f/sqrtf(fmaxf(var,0.f)+1e-5f);
  }
  __syncthreads();
  float gp[4]={0.f,0.f,0.f,0.f};
  #pragma unroll
  for(int mt=0;mt<5;++mt){
    #pragma unroll
    for(int r=0;r<4;++r){
      int row = mt*16+quad*4+r;
      float mu=mu80[row], rs=rs80[row], wk=wvS[row];
      #pragma unroll
      for(int jj=0;jj<4;++jj){
        int j = w*64 + jj*16 + col;
        float h = acc[mt][jj][r]*UNS + b1s[j];
        float x = (h-mu)*rs;
        float y = x*gs[j]+bs[j];
        float gl = 0.5f*y*(1.f+erff(y*0.70710678118654752f));
        gp[jj] += wk*gl;
      }
    }
  }
  #pragma unroll
  for(int jj=0;jj<4;++jj){ gp[jj]+=__shfl_xor(gp[jj],16,64); gp[jj]+=__shfl_xor(gp[jj],32,64); }
  if(ln<16){
    #pragma unroll
    for(int jj=0;jj<4;++jj) gfin[w*64 + jj*16 + ln] = gp[jj];
  }
  __syncthreads();
  if(tid<320){ int m=tid>>4, seg=tid&15; float p=0.f;
    for(int u=0;u<32;++u){ int j=seg*32+u; p += gfin[j]*w2[m*512+j]; }
    qred[m*16+seg]=p; }
  __syncthreads();
  if(tid<20){ float s=0.f;
    for(int seg=0;seg<16;++seg) s+=qred[tid*16+seg];
    s += b2p[tid]*wsumS;
    Qpws[(size_t)bn*20+tid]=s; }

  // opaque never-true use of ldsforce so the allocation survives DCE
  if(F[0]==1234.5678f && F[1]==-9876.5f){
    ldsforce[(tid*37)&8191] = wvS[0]+(float)tid;
    Qpws[(size_t)bn*20] += ldsforce[tid&8191];
  }
}

// ---------------- K8: per-(b,n) top-51 mask + normalize -> out1 ----------------
__global__ __launch_bounds__(256) void k8_topk(const float* F, const float* T,
                                               const float* Qpws, float* out1){
  int bn = blockIdx.x; int tid = threadIdx.x;
  int w = tid>>6, ln = tid&63;
  __shared__ float Fv[512];
  __shared__ float QpS[20];
  __shared__ float ninv[20];
  __shared__ unsigned char selb[20][64];
  for(int e=tid;e<512;e+=256) Fv[e]=F[(size_t)bn*512+e];
  if(tid<20) QpS[tid]=Qpws[(size_t)bn*20+tid];
  __syncthreads();
  for(int rr=0; rr<5; ++rr){
    int m = rr*4 + w;
    float qv[8]; uint key[8];
    const float4* tp = (const float4*)(T + (size_t)m*512 + ln*8);
    float4 t0 = tp[0], t1 = tp[1];
    float tf[8] = {t0.x,t0.y,t0.z,t0.w,t1.x,t1.y,t1.z,t1.w};
    float qp = QpS[m];
    #pragma unroll
    for(int i=0;i<8;++i){ float p = Fv[ln*8+i]*tf[i]; qv[i]=p*qp;
      key[i]=__float_as_uint(qv[i])&0x7fffffffu; }
    uint th=0u;
    for(int bit=30; bit>=0; --bit){
      uint cand = th | (1u<<bit);
      int c=0;
      #pragma unroll
      for(int i=0;i<8;++i) c += (key[i]>=cand);
      c = wsumi(c);
      if(c>=51) th=cand;
    }
    int cg=0;
    #pragma unroll
    for(int i=0;i<8;++i) cg += (key[i]>th);
    cg = wsumi(cg);
    int rneed = 51-cg;
    int eqc=0;
    #pragma unroll
    for(int i=0;i<8;++i) eqc += (key[i]==th);
    int pre=eqc;
    for(int o=1;o<64;o<<=1){ int v=__shfl_up(pre,o,64); if(ln>=o) pre+=v; }
    pre -= eqc;
    unsigned char mbits=0; float ss=0.f; int rk=pre;
    #pragma unroll
    for(int i=0;i<8;++i){
      bool s;
      if(key[i]>th) s=true;
      else if(key[i]==th){ s = (rk<rneed); rk++; }
      else s=false;
      if(s){ mbits |= (unsigned char)(1u<<i); ss += qv[i]*qv[i]; }
    }
    ss = wsumf(ss);
    if(ln==0) ninv[m] = 1.f/fmaxf(sqrtf(ss),1e-6f);
    selb[m][ln]=mbits;
  }
  __syncthreads();
  size_t base=(size_t)bn*10240;
  for(int e=tid;e<10240;e+=256){
    int d=e/20, mm=e-d*20;
    float val=0.f;
    if((selb[mm][d>>3]>>(d&7))&1){
      val = Fv[d]*T[(size_t)mm*512+d]*QpS[mm]*ninv[mm];
    }
    out1[base+e]=val;
  }
}

extern "C" void kernel_launch(void* const* d_in, const int* in_sizes, int n_in,
                              void* d_out, int out_size, void* d_ws, size_t ws_size,
                              hipStream_t stream){
  const float* F    = (const float*)d_in[0];
  const float* text = (const float*)d_in[1];
  const float* ipw  = (const float*)d_in[2];
  const float* ipb  = (const float*)d_in[3];
  const float* outw = (const float*)d_in[4];
  const float* outb = (const float*)d_in[5];
  const float* g1   = (const float*)d_in[6];
  const float* b1   = (const float*)d_in[7];
  const float* g2   = (const float*)d_in[8];
  const float* b2   = (const float*)d_in[9];
  const float* mw1  = (const float*)d_in[10];
  const float* mb1  = (const float*)d_in[11];
  const float* mlg  = (const float*)d_in[12];
  const float* mlb  = (const float*)d_in[13];
  const float* mw2  = (const float*)d_in[14];
  const float* mb2  = (const float*)d_in[15];
  const float* tmpl = (const float*)d_in[16];
  float* ws = (float*)d_ws;
  float* WT   = ws;
  float* OWT  = ws +  786432;
  float* qws  = ws + 1048576;
  float* kmat = ws + 1088000;
  float* vmat = ws + 1890816;
  float* attf = ws + 2693632;
  float* attw = ws + 3659520;
  float* ctx  = ws + 3780256;
  float* AO   = ws + 4095648;
  float* Qp   = ws + 4411040;
  _Float16* w1hi = (_Float16*)(ws + 4442400);
  _Float16* w1lo = (_Float16*)(ws + 4573472);
  float* out1 = (float*)d_out;
  float* out2 = out1 + 16056320;

  hipLaunchKernelGGL(k0_transpose, dim3(2048), dim3(256), 0, stream, ipw, outw, mw1, WT, OWT, w1hi, w1lo);
  hipLaunchKernelGGL(k1_q,   dim3(154), dim3(256), 0, stream, text, ipb, g1, b1, WT, qws);
  hipLaunchKernelGGL(k2_kv,  dim3(196), dim3(512), 0, stream, F, ipb, g1, b1, WT, kmat, vmat);
  hipLaunchKernelGGL(k3_attn,dim3(640), dim3(256), 0, stream, qws, kmat, attf);
  hipLaunchKernelGGL(k4_ctx, dim3(640), dim3(256), 0, stream, attf, vmat, ctx);
  hipLaunchKernelGGL(k5_attw,dim3(472), dim3(256), 0, stream, attf, attw, out2);
  hipLaunchKernelGGL(k6_ao,  dim3(77),  dim3(512), 0, stream, ctx, OWT, outb, g2, b2, AO);
  hipLaunchKernelGGL(k7_mlp, dim3(1568),dim3(512), 0, stream, F, AO, attw, w1hi, w1lo, mb1, mlg, mlb, mw2, mb2, Qp);
  hipLaunchKernelGGL(k8_topk,dim3(1568),dim3(256), 0, stream, F, tmpl, Qp, out1);
}